// Round 2
// baseline (759.947 us; speedup 1.0000x reference)
//
#include <hip/hip_runtime.h>

#define NB 512
#define NC 3
#define NP_ 49
#define NT_ 76
#define DD 768

typedef __attribute__((ext_vector_type(8))) short bf16x8;
typedef __attribute__((ext_vector_type(4))) float f32x4;

__device__ inline unsigned short f2bf(float x) {
    unsigned int u = __float_as_uint(x);
    u += 0x7FFFu + ((u >> 16) & 1u);   // RNE to bf16
    return (unsigned short)(u >> 16);
}
__device__ inline float bf_lo(unsigned int w) { return __uint_as_float(w << 16); }
__device__ inline float bf_hi(unsigned int w) { return __uint_as_float(w & 0xFFFF0000u); }

// ---------------------------------------------------------------------------
// Kernel 1: per-(b,ch) fused  normalize -> sim (MFMA bf16) -> K -> Sinkhorn ->
//           ot partial, atomicAdd into out[0].  grid = 1536, block = 256.
// ---------------------------------------------------------------------------
__global__ __launch_bounds__(256) void sink_kernel(const float* __restrict__ lif,
                                                   const float* __restrict__ ltf,
                                                   float* __restrict__ out) {
    const int tid = threadIdx.x;
    const int bc  = blockIdx.x;                     // b*3 + ch
    const float* ga = lif + (size_t)bc * (NP_ * DD);
    const float* gb = ltf + (size_t)bc * (NT_ * DD);

    // LDS: staging tiles (bf16, stride 72 = pad 8 to break b128 bank aliasing),
    // K matrix (stride 77), small vectors.  ~37 KB -> 4 wg/CU by LDS.
    __shared__ __attribute__((aligned(16))) unsigned short a_buf[64 * 72];
    __shared__ __attribute__((aligned(16))) unsigned short b_buf[80 * 72];
    __shared__ float Kmat[NP_ * 77];
    __shared__ float s_inv[144];
    __shared__ float r_vec[64];
    __shared__ float c_vec[80];
    __shared__ float s_err[4];
    __shared__ float s_red[4];

    // zero MFMA pad rows once (never overwritten afterwards)
    for (int idx = tid; idx < 15 * 72; idx += 256) a_buf[49 * 72 + idx] = 0;
    for (int idx = tid; idx < 4 * 72;  idx += 256) b_buf[76 * 72 + idx] = 0;

    const int wave = tid >> 6;
    const int lane = tid & 63;
    const int lr = lane & 15;      // row-within-16-tile (A) / col (B)
    const int lk = lane >> 4;      // k-group

    f32x4 acc[4][5];
    const f32x4 zero4 = {0.f, 0.f, 0.f, 0.f};
#pragma unroll
    for (int tn = 0; tn < 4; ++tn)
#pragma unroll
        for (int j = 0; j < 5; ++j) acc[tn][j] = zero4;

    float na = 0.f, nb = 0.f;

    for (int cc = 0; cc < 12; ++cc) {              // 12 chunks of 64 k's
        const int k0 = cc * 64;
        for (int idx = tid; idx < NP_ * 16; idx += 256) {
            int row = idx >> 4, q = idx & 15;
            const float4 v = *(const float4*)(ga + row * DD + k0 + q * 4);
            unsigned int w0 = (unsigned int)f2bf(v.x) | ((unsigned int)f2bf(v.y) << 16);
            unsigned int w1 = (unsigned int)f2bf(v.z) | ((unsigned int)f2bf(v.w) << 16);
            *(uint2*)(a_buf + row * 72 + q * 4) = make_uint2(w0, w1);
        }
        for (int idx = tid; idx < NT_ * 16; idx += 256) {
            int row = idx >> 4, q = idx & 15;
            const float4 v = *(const float4*)(gb + row * DD + k0 + q * 4);
            unsigned int w0 = (unsigned int)f2bf(v.x) | ((unsigned int)f2bf(v.y) << 16);
            unsigned int w1 = (unsigned int)f2bf(v.z) | ((unsigned int)f2bf(v.w) << 16);
            *(uint2*)(b_buf + row * 72 + q * 4) = make_uint2(w0, w1);
        }
        __syncthreads();
        if (wave == 0) {
            // two 16x16x32 K-steps on this chunk; A-frag: lane holds
            // A[row=lane&15][k=(lane>>4)*8 + j]; B stored [n][k] uses same map.
#pragma unroll
            for (int ks = 0; ks < 2; ++ks) {
                bf16x8 bv[5];
#pragma unroll
                for (int j = 0; j < 5; ++j)
                    bv[j] = *(const bf16x8*)(b_buf + (j * 16 + lr) * 72 + ks * 32 + lk * 8);
#pragma unroll
                for (int tn = 0; tn < 4; ++tn) {
                    bf16x8 av = *(const bf16x8*)(a_buf + (tn * 16 + lr) * 72 + ks * 32 + lk * 8);
#pragma unroll
                    for (int j = 0; j < 5; ++j)
                        acc[tn][j] = __builtin_amdgcn_mfma_f32_16x16x32_bf16(av, bv[j], acc[tn][j], 0, 0, 0);
                }
            }
        } else if (wave == 1) {
            if (lane < NP_) {       // squared norms of image tokens (bf16 data)
                const unsigned int* ap = (const unsigned int*)(a_buf + lane * 72);
#pragma unroll
                for (int k = 0; k < 32; ++k) {
                    unsigned int w = ap[k];
                    float x = bf_lo(w), y = bf_hi(w);
                    na += x * x + y * y;
                }
            }
        } else {
            int j = tid - 128;      // waves 2..3 cover 76 text tokens
            if (j < NT_) {
                const unsigned int* bp = (const unsigned int*)(b_buf + j * 72);
#pragma unroll
                for (int k = 0; k < 32; ++k) {
                    unsigned int w = bp[k];
                    float x = bf_lo(w), y = bf_hi(w);
                    nb += x * x + y * y;
                }
            }
        }
        __syncthreads();
    }

    if (wave == 1 && lane < NP_) s_inv[lane] = 1.0f / fmaxf(sqrtf(na), 1e-12f);
    if (tid >= 128 && (tid - 128) < NT_) s_inv[64 + (tid - 128)] = 1.0f / fmaxf(sqrtf(nb), 1e-12f);
    __syncthreads();

    if (wave == 0) {
        // C/D layout: col = lane&15, row = (lane>>4)*4 + reg
#pragma unroll
        for (int tn = 0; tn < 4; ++tn)
#pragma unroll
            for (int j = 0; j < 5; ++j)
#pragma unroll
                for (int rg = 0; rg < 4; ++rg) {
                    int n = tn * 16 + lk * 4 + rg;
                    int m = j * 16 + lr;
                    if (n < NP_ && m < NT_) {
                        float simv = acc[tn][j][rg] * s_inv[n] * s_inv[64 + m];
                        Kmat[n * 77 + m] = __expf((simv - 1.0f) * 10.0f);
                    }
                }
    }
    if (tid < NT_) c_vec[tid] = 1.0f;
    __syncthreads();

    // ---- Sinkhorn.  mv1: thread t -> (n = t>>2, seg = t&3, 19 m's each).
    //                 mv2: thread t -> (m = t>>1, seg = t&1, 25/24 n's each).
    const int n1 = tid >> 2, seg1 = tid & 3;
    const int n1c = (n1 < NP_) ? n1 : 0;
    float Kv1[19];
#pragma unroll
    for (int i = 0; i < 19; ++i)
        Kv1[i] = (tid < 196) ? Kmat[n1c * 77 + seg1 * 19 + i] : 0.0f;

    const int m2 = tid >> 1, seg2 = tid & 1;
    const int n2base = seg2 * 25;
    float Kv2[25];
#pragma unroll
    for (int i = 0; i < 25; ++i) {
        int nn = n2base + i;
        int nc = (nn < NP_) ? nn : 0;
        Kv2[i] = (tid < 152 && nn < NP_) ? Kmat[nc * 77 + m2] : 0.0f;
    }

    float r_old = 1.0f;
    float err;
    int iter = 0;
    do {
        float y = 0.f;
#pragma unroll
        for (int i = 0; i < 19; ++i) y += Kv1[i] * c_vec[seg1 * 19 + i];
        y += __shfl_xor(y, 1);
        y += __shfl_xor(y, 2);
        float rn = (1.0f / 49.0f) / y;
        float de = 0.f;
        if (tid < 196) {
            de = fabsf(rn - r_old);
            r_old = rn;
            if (seg1 == 0) r_vec[n1] = rn;
        }
        float e = de;
#pragma unroll
        for (int o = 1; o < 64; o <<= 1) e += __shfl_xor(e, o);
        if (lane == 0) s_err[wave] = e;
        __syncthreads();                                   // publishes r_vec + s_err
        err = (s_err[0] + s_err[1] + s_err[2] + s_err[3]) * (1.0f / (4.0f * 49.0f));

        float z = 0.f;
#pragma unroll
        for (int i = 0; i < 25; ++i) {
            int nn = n2base + i;
            z += Kv2[i] * r_vec[(nn < NP_) ? nn : 0];
        }
        z += __shfl_xor(z, 1);
        if (tid < 152 && seg2 == 0) c_vec[m2] = (1.0f / 76.0f) / z;
        ++iter;
        __syncthreads();                                   // publishes c_vec
    } while (iter < 100 && err >= 1e-3f);

    // ---- ot partial:  sum r_n c_m K_nm sim_nm,  sim = ln(K)/10 + 1
    float part = 0.f;
    for (int e0 = tid; e0 < NP_ * NT_; e0 += 256) {
        int n = e0 / NT_;
        int m = e0 - n * NT_;
        float kv = Kmat[n * 77 + m];
        part += r_vec[n] * c_vec[m] * kv * (__logf(kv) * 0.1f + 1.0f);
    }
#pragma unroll
    for (int o = 1; o < 64; o <<= 1) part += __shfl_xor(part, o);
    if (lane == 0) s_red[wave] = part;
    __syncthreads();
    if (tid == 0) atomicAdd(out, s_red[0] + s_red[1] + s_red[2] + s_red[3]);
}

// ---------------------------------------------------------------------------
// Kernel 2: logits raw dots  L[i][j] = sum_k img[i][k]*txt[j][k], K=2304.
// 64x64 tiles, K split 4 ways, atomicAdd into ws.  grid (8,8,4), block 256.
// ---------------------------------------------------------------------------
__global__ __launch_bounds__(256) void gemm_logits(const float* __restrict__ A,
                                                   const float* __restrict__ Bm,
                                                   float* __restrict__ L) {
    __shared__ __attribute__((aligned(16))) float At[64 * 36];
    __shared__ __attribute__((aligned(16))) float Bt[64 * 36];
    const int tid = threadIdx.x;
    const int i0 = blockIdx.x * 64, j0 = blockIdx.y * 64, kbase = blockIdx.z * 576;
    const int ty = tid >> 4, tx = tid & 15;
    float accv[4][4] = {};
    for (int kc = 0; kc < 18; ++kc) {
        int kb = kbase + kc * 32;
#pragma unroll
        for (int t = 0; t < 2; ++t) {
            int idx = tid + t * 256;
            int row = idx >> 3, q = idx & 7;
            *(float4*)(At + row * 36 + q * 4) =
                *(const float4*)(A + (size_t)(i0 + row) * 2304 + kb + q * 4);
            *(float4*)(Bt + row * 36 + q * 4) =
                *(const float4*)(Bm + (size_t)(j0 + row) * 2304 + kb + q * 4);
        }
        __syncthreads();
#pragma unroll 8
        for (int k = 0; k < 32; ++k) {
            float ra[4], rb[4];
#pragma unroll
            for (int a = 0; a < 4; ++a) ra[a] = At[(ty + 16 * a) * 36 + k];
#pragma unroll
            for (int b = 0; b < 4; ++b) rb[b] = Bt[(tx + 16 * b) * 36 + k];
#pragma unroll
            for (int a = 0; a < 4; ++a)
#pragma unroll
                for (int b = 0; b < 4; ++b) accv[a][b] += ra[a] * rb[b];
        }
        __syncthreads();
    }
#pragma unroll
    for (int a = 0; a < 4; ++a)
#pragma unroll
        for (int b = 0; b < 4; ++b)
            atomicAdd(L + (size_t)(i0 + ty + 16 * a) * 512 + (j0 + tx + 16 * b), accv[a][b]);
}

// ---------------------------------------------------------------------------
// Kernel 3: CE with diagonal labels, both directions.  grid 512, block 256.
// ---------------------------------------------------------------------------
__device__ inline float blk_max(float v, float* sred, int wave, int lane) {
#pragma unroll
    for (int o = 1; o < 64; o <<= 1) v = fmaxf(v, __shfl_xor(v, o));
    if (lane == 0) sred[wave] = v;
    __syncthreads();
    v = fmaxf(fmaxf(sred[0], sred[1]), fmaxf(sred[2], sred[3]));
    __syncthreads();
    return v;
}
__device__ inline float blk_sum(float v, float* sred, int wave, int lane) {
#pragma unroll
    for (int o = 1; o < 64; o <<= 1) v += __shfl_xor(v, o);
    if (lane == 0) sred[wave] = v;
    __syncthreads();
    v = sred[0] + sred[1] + sred[2] + sred[3];
    __syncthreads();
    return v;
}

__global__ __launch_bounds__(256) void ce_kernel(const float* __restrict__ L,
                                                 const float* __restrict__ lsc,
                                                 float* __restrict__ out) {
    __shared__ float sred[4];
    const int i = blockIdx.x, tid = threadIdx.x;
    const int wave = tid >> 6, lane = tid & 63;
    const float s = lsc[0] * (1.0f / 3.0f);

    float xr0 = L[(size_t)i * 512 + tid] * s;
    float xr1 = L[(size_t)i * 512 + tid + 256] * s;
    float xc0 = L[(size_t)tid * 512 + i] * s;
    float xc1 = L[(size_t)(tid + 256) * 512 + i] * s;

    float mr = blk_max(fmaxf(xr0, xr1), sred, wave, lane);
    float sr = blk_sum(__expf(xr0 - mr) + __expf(xr1 - mr), sred, wave, lane);
    float lse_r = mr + __logf(sr);

    float mc = blk_max(fmaxf(xc0, xc1), sred, wave, lane);
    float sc = blk_sum(__expf(xc0 - mc) + __expf(xc1 - mc), sred, wave, lane);
    float lse_c = mc + __logf(sc);

    if (tid == 0) {
        float dii = L[(size_t)i * 512 + i] * s;
        atomicAdd(out, (lse_r + lse_c - 2.0f * dii) * (1.0f / 1024.0f));
    }
}

extern "C" void kernel_launch(void* const* d_in, const int* in_sizes, int n_in,
                              void* d_out, int out_size, void* d_ws, size_t ws_size,
                              hipStream_t stream) {
    const float* img = (const float*)d_in[0];   // [512,3,768]
    const float* txt = (const float*)d_in[1];   // [512,3,768]
    const float* lsc = (const float*)d_in[2];   // [1]
    const float* lif = (const float*)d_in[3];   // [512,3,49,768]
    const float* ltf = (const float*)d_in[4];   // [512,3,76,768]
    float* out = (float*)d_out;
    float* Lws = (float*)d_ws;                  // 512*512 f32 = 1 MB scratch

    hipMemsetAsync(out, 0, sizeof(float), stream);
    hipMemsetAsync(Lws, 0, 512 * 512 * sizeof(float), stream);

    hipLaunchKernelGGL(gemm_logits, dim3(8, 8, 4), dim3(256), 0, stream, img, txt, Lws);
    hipLaunchKernelGGL(sink_kernel, dim3(NB * NC), dim3(256), 0, stream, lif, ltf, out);
    hipLaunchKernelGGL(ce_kernel, dim3(512), dim3(256), 0, stream, Lws, lsc, out);
}